// Round 1
// baseline (638.351 us; speedup 1.0000x reference)
//
#include <hip/hip_runtime.h>

#define SBD   384
#define NCATS 64
#define EMB   48
#define HT    256
#define HC    128
#define TB    16

// ---------------------------------------------------------------------------
// Kernel A: encode all books once into E[nbooks][48] (l2-normalized).
// 16 books per block, 256 threads.
// ---------------------------------------------------------------------------
__global__ __launch_bounds__(256) void encode_books_kernel(
    const float* __restrict__ sbert, const float* __restrict__ mh,
    const float* __restrict__ Wc1, const float* __restrict__ bc1,
    const float* __restrict__ Wc2, const float* __restrict__ bc2,
    const float* __restrict__ Wt1, const float* __restrict__ bt1,
    const float* __restrict__ Wt2, const float* __restrict__ bt2,
    float* __restrict__ E, int nbooks)
{
    __shared__ float s_in[TB][SBD];    // 24 KB sbert rows
    __shared__ float s_mh[TB][NCATS];  //  4 KB multi-hot rows
    __shared__ float s_h1t[TB][HT];    // 16 KB txt hidden
    __shared__ float s_h1c[TB][HC];    //  8 KB cat hidden
    __shared__ float s_comb[TB][EMB];  //  3 KB combined pre-norm
    __shared__ float s_rnorm[TB];

    const int t = threadIdx.x;
    const int book0 = blockIdx.x * TB;

    // ---- phase 1: stage inputs (coalesced float4, row-clamped for safety) ----
    {
        float4* dst = (float4*)&s_in[0][0];
        #pragma unroll
        for (int r = 0; r < 6; ++r) {
            int fi  = t + 256 * r;          // float4 index into 16*96
            int row = fi / (SBD / 4);
            int col = fi % (SBD / 4);
            int rc  = min(book0 + row, nbooks - 1);
            dst[fi] = ((const float4*)(sbert + (size_t)rc * SBD))[col];
        }
        {
            float4* dstm = (float4*)&s_mh[0][0];
            int fi  = t;                    // 256 float4 total
            int row = fi / (NCATS / 4);
            int col = fi % (NCATS / 4);
            int rc  = min(book0 + row, nbooks - 1);
            dstm[fi] = ((const float4*)(mh + (size_t)rc * NCATS))[col];
        }
    }
    __syncthreads();

    // ---- phase 2a: txt layer 1: h1t[b][j] = relu(sbert_b . Wt1[:,j] + bt1[j])
    // thread tile: 4 books x 4 cols. Within a wave all lanes share the book
    // group -> LDS reads broadcast; Wt1 loads are wave-coalesced float4.
    {
        const int tc = t & 63;  const int j0 = tc * 4;
        const int tr = t >> 6;  const int b0 = tr * 4;
        float acc[4][4];
        float4 bv = *(const float4*)(bt1 + j0);
        #pragma unroll
        for (int bi = 0; bi < 4; ++bi) {
            acc[bi][0] = bv.x; acc[bi][1] = bv.y; acc[bi][2] = bv.z; acc[bi][3] = bv.w;
        }
        #pragma unroll 4
        for (int k4 = 0; k4 < SBD / 4; ++k4) {
            const int k = k4 * 4;
            float4 w0 = *(const float4*)(Wt1 + (size_t)(k + 0) * HT + j0);
            float4 w1 = *(const float4*)(Wt1 + (size_t)(k + 1) * HT + j0);
            float4 w2 = *(const float4*)(Wt1 + (size_t)(k + 2) * HT + j0);
            float4 w3 = *(const float4*)(Wt1 + (size_t)(k + 3) * HT + j0);
            #pragma unroll
            for (int bi = 0; bi < 4; ++bi) {
                float4 a = ((const float4*)&s_in[b0 + bi][0])[k4];
                acc[bi][0] += a.x*w0.x + a.y*w1.x + a.z*w2.x + a.w*w3.x;
                acc[bi][1] += a.x*w0.y + a.y*w1.y + a.z*w2.y + a.w*w3.y;
                acc[bi][2] += a.x*w0.z + a.y*w1.z + a.z*w2.z + a.w*w3.z;
                acc[bi][3] += a.x*w0.w + a.y*w1.w + a.z*w2.w + a.w*w3.w;
            }
        }
        #pragma unroll
        for (int bi = 0; bi < 4; ++bi) {
            float4 o;
            o.x = fmaxf(acc[bi][0], 0.f); o.y = fmaxf(acc[bi][1], 0.f);
            o.z = fmaxf(acc[bi][2], 0.f); o.w = fmaxf(acc[bi][3], 0.f);
            *(float4*)&s_h1t[b0 + bi][j0] = o;
        }
    }

    // ---- phase 2b: cat layer 1: h1c[b][j] = relu(mh_b . Wc1[:,j] + bc1[j])
    // thread tile: 2 books x 4 cols.
    {
        const int tc = t & 31;  const int j0 = tc * 4;
        const int tr = t >> 5;  const int b0 = tr * 2;
        float acc[2][4];
        float4 bv = *(const float4*)(bc1 + j0);
        #pragma unroll
        for (int bi = 0; bi < 2; ++bi) {
            acc[bi][0] = bv.x; acc[bi][1] = bv.y; acc[bi][2] = bv.z; acc[bi][3] = bv.w;
        }
        #pragma unroll 4
        for (int k4 = 0; k4 < NCATS / 4; ++k4) {
            const int k = k4 * 4;
            float4 w0 = *(const float4*)(Wc1 + (size_t)(k + 0) * HC + j0);
            float4 w1 = *(const float4*)(Wc1 + (size_t)(k + 1) * HC + j0);
            float4 w2 = *(const float4*)(Wc1 + (size_t)(k + 2) * HC + j0);
            float4 w3 = *(const float4*)(Wc1 + (size_t)(k + 3) * HC + j0);
            #pragma unroll
            for (int bi = 0; bi < 2; ++bi) {
                float4 a = ((const float4*)&s_mh[b0 + bi][0])[k4];
                acc[bi][0] += a.x*w0.x + a.y*w1.x + a.z*w2.x + a.w*w3.x;
                acc[bi][1] += a.x*w0.y + a.y*w1.y + a.z*w2.y + a.w*w3.y;
                acc[bi][2] += a.x*w0.z + a.y*w1.z + a.z*w2.z + a.w*w3.z;
                acc[bi][3] += a.x*w0.w + a.y*w1.w + a.z*w2.w + a.w*w3.w;
            }
        }
        #pragma unroll
        for (int bi = 0; bi < 2; ++bi) {
            float4 o;
            o.x = fmaxf(acc[bi][0], 0.f); o.y = fmaxf(acc[bi][1], 0.f);
            o.z = fmaxf(acc[bi][2], 0.f); o.w = fmaxf(acc[bi][3], 0.f);
            *(float4*)&s_h1c[b0 + bi][j0] = o;
        }
    }
    __syncthreads();

    // ---- phase 3: layer 2 (no relu) + combine. 768 outputs, 3 per thread ----
    #pragma unroll
    for (int p = 0; p < 3; ++p) {
        const int idx = t + 256 * p;
        const int b = idx / EMB;
        const int d = idx % EMB;
        float at = bt2[d];
        const float4* h4 = (const float4*)&s_h1t[b][0];
        #pragma unroll 8
        for (int k4 = 0; k4 < HT / 4; ++k4) {
            float4 h = h4[k4];
            const int k = k4 * 4;
            at += h.x * Wt2[(size_t)(k + 0) * EMB + d]
                + h.y * Wt2[(size_t)(k + 1) * EMB + d]
                + h.z * Wt2[(size_t)(k + 2) * EMB + d]
                + h.w * Wt2[(size_t)(k + 3) * EMB + d];
        }
        float ac = bc2[d];
        const float4* c4 = (const float4*)&s_h1c[b][0];
        #pragma unroll 8
        for (int k4 = 0; k4 < HC / 4; ++k4) {
            float4 h = c4[k4];
            const int k = k4 * 4;
            ac += h.x * Wc2[(size_t)(k + 0) * EMB + d]
                + h.y * Wc2[(size_t)(k + 1) * EMB + d]
                + h.z * Wc2[(size_t)(k + 2) * EMB + d]
                + h.w * Wc2[(size_t)(k + 3) * EMB + d];
        }
        s_comb[b][d] = 3.0f * ac + at;
    }
    __syncthreads();

    // ---- phase 4: per-book l2 norm factors ----
    if (t < TB) {
        float ss = 0.f;
        const float* c = &s_comb[t][0];
        #pragma unroll
        for (int d = 0; d < EMB; ++d) ss += c[d] * c[d];
        s_rnorm[t] = rsqrtf(fmaxf(ss, 1e-12f));
    }
    __syncthreads();

    // ---- phase 5: write E (coalesced) ----
    #pragma unroll
    for (int p = 0; p < 3; ++p) {
        const int idx = t + 256 * p;
        const int b = idx / EMB;
        const int d = idx % EMB;
        const int gb = book0 + b;
        if (gb < nbooks) E[(size_t)gb * EMB + d] = s_comb[b][d] * s_rnorm[b];
    }
}

// ---------------------------------------------------------------------------
// Kernel B: per-sample scoring. 16 lanes per sample, 3 dims per lane ->
// each 192B gathered row is read fully coalesced by its lane group.
// ---------------------------------------------------------------------------
__global__ __launch_bounds__(256) void score_kernel(
    const int* __restrict__ user_idx, const int* __restrict__ loc_idx,
    const int* __restrict__ pos_idx,  const int* __restrict__ neg_idx,
    const float* __restrict__ ucat, const float* __restrict__ utxt,
    const float* __restrict__ lcat, const float* __restrict__ ltxt,
    const float* __restrict__ E, float* __restrict__ out, int Bn)
{
    const int t    = threadIdx.x;
    const int lane = t & 15;
    const int s    = blockIdx.x * 16 + (t >> 4);
    if (s >= Bn) return;

    const int ui = user_idx[s];
    const int li = loc_idx[s];
    const int pi = pos_idx[s];
    const int ni = neg_idx[s];

    const int d0 = lane * 3;
    const float* uc = ucat + (size_t)ui * EMB + d0;
    const float* ut = utxt + (size_t)ui * EMB + d0;
    const float* lc = lcat + (size_t)li * EMB + d0;
    const float* lt = ltxt + (size_t)li * EMB + d0;
    const float* pp = E + (size_t)pi * EMB + d0;
    const float* nn = E + (size_t)ni * EMB + d0;

    float u0 = 3.0f * (uc[0] + lc[0]) + (ut[0] + lt[0]);
    float u1 = 3.0f * (uc[1] + lc[1]) + (ut[1] + lt[1]);
    float u2 = 3.0f * (uc[2] + lc[2]) + (ut[2] + lt[2]);

    float usq = u0 * u0 + u1 * u1 + u2 * u2;
    float ps  = u0 * pp[0] + u1 * pp[1] + u2 * pp[2];
    float ns  = u0 * nn[0] + u1 * nn[1] + u2 * nn[2];

    #pragma unroll
    for (int m = 1; m < 16; m <<= 1) {
        usq += __shfl_xor(usq, m);
        ps  += __shfl_xor(ps, m);
        ns  += __shfl_xor(ns, m);
    }

    if (lane == 0) {
        const float inv = rsqrtf(fmaxf(usq, 1e-12f)) * 20.0f;  // /TEMP, TEMP=0.05
        out[2 * (size_t)s + 0] = ps * inv;
        out[2 * (size_t)s + 1] = ns * inv;
    }
}

extern "C" void kernel_launch(void* const* d_in, const int* in_sizes, int n_in,
                              void* d_out, int out_size, void* d_ws, size_t ws_size,
                              hipStream_t stream) {
    const int*   user_idx = (const int*)d_in[0];
    const int*   loc_idx  = (const int*)d_in[1];
    const int*   pos_idx  = (const int*)d_in[2];
    const int*   neg_idx  = (const int*)d_in[3];
    const float* ucat     = (const float*)d_in[4];
    const float* utxt     = (const float*)d_in[5];
    const float* lcat     = (const float*)d_in[6];
    const float* ltxt     = (const float*)d_in[7];
    const float* sbert    = (const float*)d_in[8];
    const float* mh       = (const float*)d_in[9];
    const float* Wc1      = (const float*)d_in[10];
    const float* bc1      = (const float*)d_in[11];
    const float* Wc2      = (const float*)d_in[12];
    const float* bc2      = (const float*)d_in[13];
    const float* Wt1      = (const float*)d_in[14];
    const float* bt1      = (const float*)d_in[15];
    const float* Wt2      = (const float*)d_in[16];
    const float* bt2      = (const float*)d_in[17];

    const int Bn     = in_sizes[0];
    const int nbooks = in_sizes[8] / SBD;

    float* E = (float*)d_ws;  // nbooks * 48 floats = 19.2 MB

    const int nblocksA = (nbooks + TB - 1) / TB;
    hipLaunchKernelGGL(encode_books_kernel, dim3(nblocksA), dim3(256), 0, stream,
                       sbert, mh, Wc1, bc1, Wc2, bc2, Wt1, bt1, Wt2, bt2, E, nbooks);

    const int nblocksB = (Bn + 15) / 16;
    hipLaunchKernelGGL(score_kernel, dim3(nblocksB), dim3(256), 0, stream,
                       user_idx, loc_idx, pos_idx, neg_idx,
                       ucat, utxt, lcat, ltxt, E, (float*)d_out, Bn);
}

// Round 2
// 251.525 us; speedup vs baseline: 2.5379x; 2.5379x over previous
//
#include <hip/hip_runtime.h>

#define SBD   384
#define NCATS 64
#define EMB   48
#define HT    256
#define HC    128
#define MB    64     // books per block

typedef __attribute__((ext_vector_type(8))) short short8;
typedef __attribute__((ext_vector_type(4))) float f32x4;

__device__ __forceinline__ short f2bf(float x) {
    union { float f; unsigned u; } v; v.f = x;
    unsigned r = v.u + 0x7FFF + ((v.u >> 16) & 1);   // round-to-nearest-even
    return (short)(r >> 16);
}

// ---------------------------------------------------------------------------
// Prep: transpose weights to bf16 [N][K] so MFMA B-frags are contiguous-k.
// ---------------------------------------------------------------------------
__global__ void prep_weights(const float* __restrict__ Wt1, const float* __restrict__ Wt2,
                             const float* __restrict__ Wc1, const float* __restrict__ Wc2,
                             short* __restrict__ Wt1T, short* __restrict__ Wt2T,
                             short* __restrict__ Wc1T, short* __restrict__ Wc2T) {
    int t = blockIdx.x * blockDim.x + threadIdx.x;
    int stride = gridDim.x * blockDim.x;
    for (int i = t; i < SBD * HT; i += stride) { int k = i / HT, n = i % HT; Wt1T[(size_t)n * SBD + k] = f2bf(Wt1[i]); }
    for (int i = t; i < HT * EMB; i += stride) { int k = i / EMB, n = i % EMB; Wt2T[(size_t)n * HT + k] = f2bf(Wt2[i]); }
    for (int i = t; i < NCATS * HC; i += stride) { int k = i / HC, n = i % HC; Wc1T[(size_t)n * NCATS + k] = f2bf(Wc1[i]); }
    for (int i = t; i < HC * EMB; i += stride) { int k = i / EMB, n = i % EMB; Wc2T[(size_t)n * HC + k] = f2bf(Wc2[i]); }
}

// ---------------------------------------------------------------------------
// Encoder: 64 books/block, 4 waves, wave w owns rows 16w..16w+15.
// LDS: s_A bf16[64][384] swz @0 (48K); H1t bf16[64][256] swz @48K (32K).
// s_mh bf16[64][64] swz @0 (8K) and H1c bf16[64][128] swz @8K (16K) alias s_A.
// XOR swizzle: byte ^= (row&7)<<4  (all row strides are multiples of 256B).
// ---------------------------------------------------------------------------
__global__ __launch_bounds__(256, 2) void encode_books_mfma(
    const float* __restrict__ sbert, const float* __restrict__ mh,
    const short* __restrict__ Wt1T, const float* __restrict__ bt1,
    const short* __restrict__ Wt2T, const float* __restrict__ bt2,
    const short* __restrict__ Wc1T, const float* __restrict__ bc1,
    const short* __restrict__ Wc2T, const float* __restrict__ bc2,
    float* __restrict__ E, int nbooks)
{
    __shared__ char lds[81920];

    const int t  = threadIdx.x;
    const int w  = t >> 6;
    const int l  = t & 63;
    const int lr = l & 15;        // MFMA row/col within 16
    const int lg = l >> 4;        // k-group
    const int book0 = blockIdx.x * MB;
    const int arow  = w * 16 + lr;          // A-frag row (block-local)
    const int drow0 = w * 16 + lg * 4;      // D-frag first row (block-local)

    // ---- stage sbert tile -> bf16 LDS (swizzled) ----
    #pragma unroll
    for (int i = 0; i < 24; ++i) {
        int fi  = t + 256 * i;              // 64*96 float4 chunks
        int row = fi / (SBD / 4);
        int c4  = fi % (SBD / 4);
        int rb  = min(book0 + row, nbooks - 1);
        float4 v = ((const float4*)(sbert + (size_t)rb * SBD))[c4];
        ushort4 h;
        h.x = (unsigned short)f2bf(v.x); h.y = (unsigned short)f2bf(v.y);
        h.z = (unsigned short)f2bf(v.z); h.w = (unsigned short)f2bf(v.w);
        int boff = (row * 768 + c4 * 8) ^ ((row & 7) << 4);
        *(ushort4*)(lds + boff) = h;
    }
    __syncthreads();

    // ---- txt layer 1: [64x384] @ [384x256], acc over 16 n-tiles ----
    f32x4 acc[16];
    #pragma unroll
    for (int nt = 0; nt < 16; ++nt) {
        float b = bt1[nt * 16 + lr];
        acc[nt] = (f32x4){b, b, b, b};
    }
    for (int ks = 0; ks < 12; ++ks) {
        int aoff = (arow * 768 + (lg * 8 + ks * 32) * 2) ^ ((arow & 7) << 4);
        short8 af = *(const short8*)(lds + aoff);
        #pragma unroll
        for (int nt = 0; nt < 16; ++nt) {
            short8 bf = *(const short8*)(Wt1T + (size_t)(nt * 16 + lr) * SBD + lg * 8 + ks * 32);
            acc[nt] = __builtin_amdgcn_mfma_f32_16x16x32_bf16(af, bf, acc[nt], 0, 0, 0);
        }
    }
    __syncthreads();   // all waves done reading s_A

    // relu -> bf16 -> H1t (swizzled), rows are this wave's own
    #pragma unroll
    for (int nt = 0; nt < 16; ++nt) {
        #pragma unroll
        for (int r = 0; r < 4; ++r) {
            int row = drow0 + r;
            int col = nt * 16 + lr;
            int boff = 49152 + ((row * 512 + col * 2) ^ ((row & 7) << 4));
            *(unsigned short*)(lds + boff) = (unsigned short)f2bf(fmaxf(acc[nt][r], 0.f));
        }
    }

    // ---- stage mh tile -> bf16 LDS @0 (aliases s_A, now dead) ----
    #pragma unroll
    for (int i = 0; i < 4; ++i) {
        int fi  = t + 256 * i;              // 64*16 float4 chunks
        int row = fi / (NCATS / 4);
        int c4  = fi % (NCATS / 4);
        int rb  = min(book0 + row, nbooks - 1);
        float4 v = ((const float4*)(mh + (size_t)rb * NCATS))[c4];
        ushort4 h;
        h.x = (unsigned short)f2bf(v.x); h.y = (unsigned short)f2bf(v.y);
        h.z = (unsigned short)f2bf(v.z); h.w = (unsigned short)f2bf(v.w);
        int boff = (row * 128 + c4 * 8) ^ ((row & 7) << 4);
        *(ushort4*)(lds + boff) = h;
    }
    __syncthreads();

    // ---- txt layer 2: [64x256] @ [256x48], 3 n-tiles ----
    f32x4 acct[3];
    #pragma unroll
    for (int nt = 0; nt < 3; ++nt) {
        float b = bt2[nt * 16 + lr];
        acct[nt] = (f32x4){b, b, b, b};
    }
    #pragma unroll
    for (int ks = 0; ks < 8; ++ks) {
        int aoff = 49152 + ((arow * 512 + (lg * 8 + ks * 32) * 2) ^ ((arow & 7) << 4));
        short8 af = *(const short8*)(lds + aoff);
        #pragma unroll
        for (int nt = 0; nt < 3; ++nt) {
            short8 bf = *(const short8*)(Wt2T + (size_t)(nt * 16 + lr) * HT + lg * 8 + ks * 32);
            acct[nt] = __builtin_amdgcn_mfma_f32_16x16x32_bf16(af, bf, acct[nt], 0, 0, 0);
        }
    }

    // ---- cat layer 1: [64x64] @ [64x128], 8 n-tiles ----
    f32x4 accc[8];
    #pragma unroll
    for (int nt = 0; nt < 8; ++nt) {
        float b = bc1[nt * 16 + lr];
        accc[nt] = (f32x4){b, b, b, b};
    }
    #pragma unroll
    for (int ks = 0; ks < 2; ++ks) {
        int aoff = (arow * 128 + (lg * 8 + ks * 32) * 2) ^ ((arow & 7) << 4);
        short8 af = *(const short8*)(lds + aoff);
        #pragma unroll
        for (int nt = 0; nt < 8; ++nt) {
            short8 bf = *(const short8*)(Wc1T + (size_t)(nt * 16 + lr) * NCATS + lg * 8 + ks * 32);
            accc[nt] = __builtin_amdgcn_mfma_f32_16x16x32_bf16(af, bf, accc[nt], 0, 0, 0);
        }
    }
    __syncthreads();   // everyone done reading s_mh before... (H1c disjoint, but keep ordering safe)

    // relu -> bf16 -> H1c @8K (swizzled)
    #pragma unroll
    for (int nt = 0; nt < 8; ++nt) {
        #pragma unroll
        for (int r = 0; r < 4; ++r) {
            int row = drow0 + r;
            int col = nt * 16 + lr;
            int boff = 8192 + ((row * 256 + col * 2) ^ ((row & 7) << 4));
            *(unsigned short*)(lds + boff) = (unsigned short)f2bf(fmaxf(accc[nt][r], 0.f));
        }
    }
    __syncthreads();

    // ---- cat layer 2: [64x128] @ [128x48], 3 n-tiles ----
    f32x4 acc2[3];
    #pragma unroll
    for (int nt = 0; nt < 3; ++nt) {
        float b = bc2[nt * 16 + lr];
        acc2[nt] = (f32x4){b, b, b, b};
    }
    #pragma unroll
    for (int ks = 0; ks < 4; ++ks) {
        int aoff = 8192 + ((arow * 256 + (lg * 8 + ks * 32) * 2) ^ ((arow & 7) << 4));
        short8 af = *(const short8*)(lds + aoff);
        #pragma unroll
        for (int nt = 0; nt < 3; ++nt) {
            short8 bf = *(const short8*)(Wc2T + (size_t)(nt * 16 + lr) * HC + lg * 8 + ks * 32);
            acc2[nt] = __builtin_amdgcn_mfma_f32_16x16x32_bf16(af, bf, acc2[nt], 0, 0, 0);
        }
    }

    // ---- combine (3*cat + txt), l2norm per row, store E fp32 ----
    f32x4 comb[3];
    #pragma unroll
    for (int nt = 0; nt < 3; ++nt) {
        #pragma unroll
        for (int r = 0; r < 4; ++r) comb[nt][r] = 3.0f * acc2[nt][r] + acct[nt][r];
    }
    float rn[4];
    #pragma unroll
    for (int r = 0; r < 4; ++r) {
        float ss = comb[0][r] * comb[0][r] + comb[1][r] * comb[1][r] + comb[2][r] * comb[2][r];
        ss += __shfl_xor(ss, 1);
        ss += __shfl_xor(ss, 2);
        ss += __shfl_xor(ss, 4);
        ss += __shfl_xor(ss, 8);
        rn[r] = rsqrtf(fmaxf(ss, 1e-12f));
    }
    #pragma unroll
    for (int nt = 0; nt < 3; ++nt) {
        #pragma unroll
        for (int r = 0; r < 4; ++r) {
            int grow = book0 + drow0 + r;
            if (grow < nbooks) E[(size_t)grow * EMB + nt * 16 + lr] = comb[nt][r] * rn[r];
        }
    }
}

// ---------------------------------------------------------------------------
// Scoring: 16 lanes per sample, 3 dims/lane, shuffle-reduce.
// ---------------------------------------------------------------------------
__global__ __launch_bounds__(256) void score_kernel(
    const int* __restrict__ user_idx, const int* __restrict__ loc_idx,
    const int* __restrict__ pos_idx,  const int* __restrict__ neg_idx,
    const float* __restrict__ ucat, const float* __restrict__ utxt,
    const float* __restrict__ lcat, const float* __restrict__ ltxt,
    const float* __restrict__ E, float* __restrict__ out, int Bn)
{
    const int t    = threadIdx.x;
    const int lane = t & 15;
    const int s    = blockIdx.x * 16 + (t >> 4);
    if (s >= Bn) return;

    const int ui = user_idx[s];
    const int li = loc_idx[s];
    const int pi = pos_idx[s];
    const int ni = neg_idx[s];

    const int d0 = lane * 3;
    const float* uc = ucat + (size_t)ui * EMB + d0;
    const float* ut = utxt + (size_t)ui * EMB + d0;
    const float* lc = lcat + (size_t)li * EMB + d0;
    const float* lt = ltxt + (size_t)li * EMB + d0;
    const float* pp = E + (size_t)pi * EMB + d0;
    const float* nn = E + (size_t)ni * EMB + d0;

    float u0 = 3.0f * (uc[0] + lc[0]) + (ut[0] + lt[0]);
    float u1 = 3.0f * (uc[1] + lc[1]) + (ut[1] + lt[1]);
    float u2 = 3.0f * (uc[2] + lc[2]) + (ut[2] + lt[2]);

    float usq = u0 * u0 + u1 * u1 + u2 * u2;
    float ps  = u0 * pp[0] + u1 * pp[1] + u2 * pp[2];
    float ns  = u0 * nn[0] + u1 * nn[1] + u2 * nn[2];

    #pragma unroll
    for (int m = 1; m < 16; m <<= 1) {
        usq += __shfl_xor(usq, m);
        ps  += __shfl_xor(ps, m);
        ns  += __shfl_xor(ns, m);
    }

    if (lane == 0) {
        const float inv = rsqrtf(fmaxf(usq, 1e-12f)) * 20.0f;  // /TEMP
        out[2 * (size_t)s + 0] = ps * inv;
        out[2 * (size_t)s + 1] = ns * inv;
    }
}

extern "C" void kernel_launch(void* const* d_in, const int* in_sizes, int n_in,
                              void* d_out, int out_size, void* d_ws, size_t ws_size,
                              hipStream_t stream) {
    const int*   user_idx = (const int*)d_in[0];
    const int*   loc_idx  = (const int*)d_in[1];
    const int*   pos_idx  = (const int*)d_in[2];
    const int*   neg_idx  = (const int*)d_in[3];
    const float* ucat     = (const float*)d_in[4];
    const float* utxt     = (const float*)d_in[5];
    const float* lcat     = (const float*)d_in[6];
    const float* ltxt     = (const float*)d_in[7];
    const float* sbert    = (const float*)d_in[8];
    const float* mh       = (const float*)d_in[9];
    const float* Wc1      = (const float*)d_in[10];
    const float* bc1      = (const float*)d_in[11];
    const float* Wc2      = (const float*)d_in[12];
    const float* bc2      = (const float*)d_in[13];
    const float* Wt1      = (const float*)d_in[14];
    const float* bt1      = (const float*)d_in[15];
    const float* Wt2      = (const float*)d_in[16];
    const float* bt2      = (const float*)d_in[17];

    const int Bn     = in_sizes[0];
    const int nbooks = in_sizes[8] / SBD;

    char* ws = (char*)d_ws;
    float* E = (float*)ws;
    size_t off = (size_t)nbooks * EMB * 4;          // E: fp32 [nbooks][48]
    off = (off + 255) & ~(size_t)255;
    short* Wt1T = (short*)(ws + off); off += (size_t)HT * SBD * 2;
    short* Wt2T = (short*)(ws + off); off += (size_t)EMB * HT * 2;
    short* Wc1T = (short*)(ws + off); off += (size_t)HC * NCATS * 2;
    short* Wc2T = (short*)(ws + off);

    hipLaunchKernelGGL(prep_weights, dim3(128), dim3(256), 0, stream,
                       Wt1, Wt2, Wc1, Wc2, Wt1T, Wt2T, Wc1T, Wc2T);

    const int nblocksA = (nbooks + MB - 1) / MB;
    hipLaunchKernelGGL(encode_books_mfma, dim3(nblocksA), dim3(256), 0, stream,
                       sbert, mh, Wt1T, bt1, Wt2T, bt2, Wc1T, bc1, Wc2T, bc2, E, nbooks);

    const int nblocksB = (Bn + 15) / 16;
    hipLaunchKernelGGL(score_kernel, dim3(nblocksB), dim3(256), 0, stream,
                       user_idx, loc_idx, pos_idx, neg_idx,
                       ucat, utxt, lcat, ltxt, E, (float*)d_out, Bn);
}

// Round 3
// 117.818 us; speedup vs baseline: 5.4181x; 2.1349x over previous
//
#include <hip/hip_runtime.h>

#define SBD   384
#define NCATS 64
#define EMB   48
#define HT    256
#define HC    128
#define MB    64     // books per block

typedef __attribute__((ext_vector_type(8))) short short8;
typedef __attribute__((ext_vector_type(4))) float f32x4;

__device__ __forceinline__ short f2bf(float x) {
    union { float f; unsigned u; } v; v.f = x;
    unsigned r = v.u + 0x7FFF + ((v.u >> 16) & 1);   // RNE
    return (short)(r >> 16);
}

// async global->LDS, 16B per lane, dest = wave-uniform base + lane*16
__device__ __forceinline__ void glds16(const void* g, void* l) {
    __builtin_amdgcn_global_load_lds((const __attribute__((address_space(1))) void*)g,
                                     (__attribute__((address_space(3))) void*)l, 16, 0, 0);
}

// ---------------------------------------------------------------------------
// Prep: write weights as bf16 pre-swizzled LDS byte-images.
// Swizzle (all tiles): byte ^= (row&7)<<4, row = N-index, contiguous-K rows.
// iT1: 12 chunks of [256n][32k]  (16 KB each, 192 KB)
// iT2: [48n][256k] (24 KB) ; iC1: [128n][64k] (16 KB) ; iC2: [48n][128k] (12 KB)
// ---------------------------------------------------------------------------
__global__ void prep_weights(const float* __restrict__ Wt1, const float* __restrict__ Wt2,
                             const float* __restrict__ Wc1, const float* __restrict__ Wc2,
                             char* __restrict__ iT1, char* __restrict__ iT2,
                             char* __restrict__ iC1, char* __restrict__ iC2) {
    int t = blockIdx.x * blockDim.x + threadIdx.x;
    int stride = gridDim.x * blockDim.x;
    for (int g = t; g < 256 * 48; g += stride) {       // Wt1 [384k][256n]
        int n = g / 48, k0 = (g - n * 48) * 8;
        int c = k0 >> 5, kin = k0 & 31;
        short8 v;
        #pragma unroll
        for (int j = 0; j < 8; ++j) v[j] = f2bf(Wt1[(size_t)(k0 + j) * HT + n]);
        *(short8*)(iT1 + (size_t)c * 16384 + ((n * 64 + kin * 2) ^ ((n & 7) << 4))) = v;
    }
    for (int g = t; g < 48 * 32; g += stride) {        // Wt2 [256k][48n]
        int n = g / 32, k0 = (g - n * 32) * 8;
        short8 v;
        #pragma unroll
        for (int j = 0; j < 8; ++j) v[j] = f2bf(Wt2[(size_t)(k0 + j) * EMB + n]);
        *(short8*)(iT2 + ((n * 512 + k0 * 2) ^ ((n & 7) << 4))) = v;
    }
    for (int g = t; g < 128 * 8; g += stride) {        // Wc1 [64k][128n]
        int n = g / 8, k0 = (g - n * 8) * 8;
        short8 v;
        #pragma unroll
        for (int j = 0; j < 8; ++j) v[j] = f2bf(Wc1[(size_t)(k0 + j) * HC + n]);
        *(short8*)(iC1 + ((n * 128 + k0 * 2) ^ ((n & 7) << 4))) = v;
    }
    for (int g = t; g < 48 * 16; g += stride) {        // Wc2 [128k][48n]
        int n = g / 16, k0 = (g - n * 16) * 8;
        short8 v;
        #pragma unroll
        for (int j = 0; j < 8; ++j) v[j] = f2bf(Wc2[(size_t)(k0 + j) * EMB + n]);
        *(short8*)(iC2 + ((n * 256 + k0 * 2) ^ ((n & 7) << 4))) = v;
    }
}

// ---------------------------------------------------------------------------
// Encoder. LDS map (72 KB -> 2 blocks/CU):
//   [0,8K)    A dbuf: 2 x 4KB  [64m][32k] bf16 swz   (later: mh [64][64] 8KB)
//   [8K,40K)  B dbuf: 2 x 16KB (L1txt chunks)        (later: T2 24KB / C1 16KB + C2 12KB @24K)
//   [40K,72K) H1t [64][256] bf16 swz 32KB            (later: H1c [64][128] 16KB)
// ---------------------------------------------------------------------------
__global__ __launch_bounds__(256, 2) void encode_books_mfma(
    const float* __restrict__ sbert, const float* __restrict__ mh,
    const char* __restrict__ iT1, const char* __restrict__ iT2,
    const char* __restrict__ iC1, const char* __restrict__ iC2,
    const float* __restrict__ bt1, const float* __restrict__ bt2,
    const float* __restrict__ bc1, const float* __restrict__ bc2,
    float* __restrict__ E, int nbooks)
{
    __shared__ char lds[73728];

    const int t  = threadIdx.x;
    const int w  = t >> 6;
    const int l  = t & 63;
    const int lr = l & 15;
    const int lg = l >> 4;
    const int book0 = blockIdx.x * MB;
    const int arow  = w * 16 + lr;
    const int drow0 = w * 16 + lg * 4;
    const int aswz  = (arow & 7) << 4;
    const int nswz  = (lr & 7) << 4;     // (nt*16+lr)&7 == lr&7

    auto stageA = [&](int c, int buf) {  // sbert k-chunk [64][32] -> bf16 swz
        int row = t >> 2, k0 = (t & 3) * 8;
        int rb = min(book0 + row, nbooks - 1);
        const float* s = sbert + (size_t)rb * SBD + c * 32 + k0;
        float4 v0 = *(const float4*)s, v1 = *(const float4*)(s + 4);
        short8 h;
        h[0] = f2bf(v0.x); h[1] = f2bf(v0.y); h[2] = f2bf(v0.z); h[3] = f2bf(v0.w);
        h[4] = f2bf(v1.x); h[5] = f2bf(v1.y); h[6] = f2bf(v1.z); h[7] = f2bf(v1.w);
        *(short8*)(lds + buf * 4096 + ((row * 64 + k0 * 2) ^ ((row & 7) << 4))) = h;
    };
    auto stageB = [&](const char* img, int dst, int bytes) {  // linear image copy
        int perw = bytes >> 2;           // bytes per wave (4 waves)
        for (int i = 0; i < perw; i += 1024)
            glds16(img + w * perw + i + l * 16, lds + dst + w * perw + i);
    };

    // ======== L1 txt: C1[64][256] = A[64][384] @ Wt1, 12 k-chunks dbuf ========
    f32x4 acc[16];
    #pragma unroll
    for (int nt = 0; nt < 16; ++nt) { float b = bt1[nt * 16 + lr]; acc[nt] = (f32x4){b, b, b, b}; }

    stageA(0, 0);
    stageB(iT1, 8192, 16384);
    __syncthreads();
    for (int c = 0; c < 12; ++c) {
        const int cur = c & 1;
        if (c < 11) {
            stageA(c + 1, cur ^ 1);
            stageB(iT1 + (size_t)(c + 1) * 16384, 8192 + (cur ^ 1) * 16384, 16384);
        }
        short8 af = *(const short8*)(lds + cur * 4096 + ((arow * 64 + lg * 16) ^ aswz));
        #pragma unroll
        for (int nt = 0; nt < 16; ++nt) {
            short8 bf = *(const short8*)(lds + 8192 + cur * 16384 +
                                         (((nt * 16 + lr) * 64 + lg * 16) ^ nswz));
            acc[nt] = __builtin_amdgcn_mfma_f32_16x16x32_bf16(af, bf, acc[nt], 0, 0, 0);
        }
        __syncthreads();
    }

    // ======== H1t (relu->bf16->LDS) + stage Wt2 + stage mh ========
    #pragma unroll
    for (int nt = 0; nt < 16; ++nt) {
        #pragma unroll
        for (int r = 0; r < 4; ++r) {
            int row = drow0 + r, col = nt * 16 + lr;
            *(unsigned short*)(lds + 40960 + ((row * 512 + col * 2) ^ ((row & 7) << 4))) =
                (unsigned short)f2bf(fmaxf(acc[nt][r], 0.f));
        }
    }
    stageB(iT2, 8192, 24576);
    #pragma unroll
    for (int i = 0; i < 2; ++i) {        // mh [64][64] -> bf16 swz @0
        int g = t + 256 * i;
        int row = g >> 3, k0 = (g & 7) * 8;
        int rb = min(book0 + row, nbooks - 1);
        const float* s = mh + (size_t)rb * NCATS + k0;
        float4 v0 = *(const float4*)s, v1 = *(const float4*)(s + 4);
        short8 h;
        h[0] = f2bf(v0.x); h[1] = f2bf(v0.y); h[2] = f2bf(v0.z); h[3] = f2bf(v0.w);
        h[4] = f2bf(v1.x); h[5] = f2bf(v1.y); h[6] = f2bf(v1.z); h[7] = f2bf(v1.w);
        *(short8*)(lds + ((row * 128 + k0 * 2) ^ ((row & 7) << 4))) = h;
    }
    __syncthreads();

    // ======== L2 txt: [64][48] = H1t[64][256] @ Wt2 ========
    f32x4 acct[3];
    #pragma unroll
    for (int nt = 0; nt < 3; ++nt) { float b = bt2[nt * 16 + lr]; acct[nt] = (f32x4){b, b, b, b}; }
    #pragma unroll
    for (int ks = 0; ks < 8; ++ks) {
        short8 af = *(const short8*)(lds + 40960 + ((arow * 512 + (lg * 8 + ks * 32) * 2) ^ aswz));
        #pragma unroll
        for (int nt = 0; nt < 3; ++nt) {
            short8 bf = *(const short8*)(lds + 8192 +
                (((nt * 16 + lr) * 512 + (lg * 8 + ks * 32) * 2) ^ nswz));
            acct[nt] = __builtin_amdgcn_mfma_f32_16x16x32_bf16(af, bf, acct[nt], 0, 0, 0);
        }
    }
    __syncthreads();

    stageB(iC1, 8192, 16384);
    stageB(iC2, 24576, 12288);
    __syncthreads();

    // ======== L1 cat: [64][128] = mh[64][64] @ Wc1 ========
    f32x4 accc[8];
    #pragma unroll
    for (int nt = 0; nt < 8; ++nt) { float b = bc1[nt * 16 + lr]; accc[nt] = (f32x4){b, b, b, b}; }
    #pragma unroll
    for (int ks = 0; ks < 2; ++ks) {
        short8 af = *(const short8*)(lds + ((arow * 128 + (lg * 8 + ks * 32) * 2) ^ aswz));
        #pragma unroll
        for (int nt = 0; nt < 8; ++nt) {
            short8 bf = *(const short8*)(lds + 8192 +
                (((nt * 16 + lr) * 128 + (lg * 8 + ks * 32) * 2) ^ nswz));
            accc[nt] = __builtin_amdgcn_mfma_f32_16x16x32_bf16(af, bf, accc[nt], 0, 0, 0);
        }
    }
    // H1c -> [40K,56K) (H1t dead since L2txt done)
    #pragma unroll
    for (int nt = 0; nt < 8; ++nt) {
        #pragma unroll
        for (int r = 0; r < 4; ++r) {
            int row = drow0 + r, col = nt * 16 + lr;
            *(unsigned short*)(lds + 40960 + ((row * 256 + col * 2) ^ ((row & 7) << 4))) =
                (unsigned short)f2bf(fmaxf(accc[nt][r], 0.f));
        }
    }
    __syncthreads();

    // ======== L2 cat: [64][48] = H1c[64][128] @ Wc2 ========
    f32x4 acc2[3];
    #pragma unroll
    for (int nt = 0; nt < 3; ++nt) { float b = bc2[nt * 16 + lr]; acc2[nt] = (f32x4){b, b, b, b}; }
    #pragma unroll
    for (int ks = 0; ks < 4; ++ks) {
        short8 af = *(const short8*)(lds + 40960 + ((arow * 256 + (lg * 8 + ks * 32) * 2) ^ aswz));
        #pragma unroll
        for (int nt = 0; nt < 3; ++nt) {
            short8 bf = *(const short8*)(lds + 24576 +
                (((nt * 16 + lr) * 256 + (lg * 8 + ks * 32) * 2) ^ nswz));
            acc2[nt] = __builtin_amdgcn_mfma_f32_16x16x32_bf16(af, bf, acc2[nt], 0, 0, 0);
        }
    }

    // ======== combine, l2norm, store ========
    f32x4 comb[3];
    #pragma unroll
    for (int nt = 0; nt < 3; ++nt)
        #pragma unroll
        for (int r = 0; r < 4; ++r) comb[nt][r] = 3.0f * acc2[nt][r] + acct[nt][r];
    float rn[4];
    #pragma unroll
    for (int r = 0; r < 4; ++r) {
        float ss = comb[0][r] * comb[0][r] + comb[1][r] * comb[1][r] + comb[2][r] * comb[2][r];
        ss += __shfl_xor(ss, 1); ss += __shfl_xor(ss, 2);
        ss += __shfl_xor(ss, 4); ss += __shfl_xor(ss, 8);
        rn[r] = rsqrtf(fmaxf(ss, 1e-12f));
    }
    #pragma unroll
    for (int nt = 0; nt < 3; ++nt) {
        #pragma unroll
        for (int r = 0; r < 4; ++r) {
            int grow = book0 + drow0 + r;
            if (grow < nbooks) E[(size_t)grow * EMB + nt * 16 + lr] = comb[nt][r] * rn[r];
        }
    }
}

// ---------------------------------------------------------------------------
// Scoring: 16 lanes/sample, 3 dims/lane, shuffle-reduce.
// ---------------------------------------------------------------------------
__global__ __launch_bounds__(256) void score_kernel(
    const int* __restrict__ user_idx, const int* __restrict__ loc_idx,
    const int* __restrict__ pos_idx,  const int* __restrict__ neg_idx,
    const float* __restrict__ ucat, const float* __restrict__ utxt,
    const float* __restrict__ lcat, const float* __restrict__ ltxt,
    const float* __restrict__ E, float* __restrict__ out, int Bn)
{
    const int t    = threadIdx.x;
    const int lane = t & 15;
    const int s    = blockIdx.x * 16 + (t >> 4);
    if (s >= Bn) return;

    const int ui = user_idx[s];
    const int li = loc_idx[s];
    const int pi = pos_idx[s];
    const int ni = neg_idx[s];

    const int d0 = lane * 3;
    const float* uc = ucat + (size_t)ui * EMB + d0;
    const float* ut = utxt + (size_t)ui * EMB + d0;
    const float* lc = lcat + (size_t)li * EMB + d0;
    const float* lt = ltxt + (size_t)li * EMB + d0;
    const float* pp = E + (size_t)pi * EMB + d0;
    const float* nn = E + (size_t)ni * EMB + d0;

    float u0 = 3.0f * (uc[0] + lc[0]) + (ut[0] + lt[0]);
    float u1 = 3.0f * (uc[1] + lc[1]) + (ut[1] + lt[1]);
    float u2 = 3.0f * (uc[2] + lc[2]) + (ut[2] + lt[2]);

    float usq = u0 * u0 + u1 * u1 + u2 * u2;
    float ps  = u0 * pp[0] + u1 * pp[1] + u2 * pp[2];
    float ns  = u0 * nn[0] + u1 * nn[1] + u2 * nn[2];

    #pragma unroll
    for (int m = 1; m < 16; m <<= 1) {
        usq += __shfl_xor(usq, m);
        ps  += __shfl_xor(ps, m);
        ns  += __shfl_xor(ns, m);
    }

    if (lane == 0) {
        const float inv = rsqrtf(fmaxf(usq, 1e-12f)) * 20.0f;  // /TEMP
        out[2 * (size_t)s + 0] = ps * inv;
        out[2 * (size_t)s + 1] = ns * inv;
    }
}

extern "C" void kernel_launch(void* const* d_in, const int* in_sizes, int n_in,
                              void* d_out, int out_size, void* d_ws, size_t ws_size,
                              hipStream_t stream) {
    const int*   user_idx = (const int*)d_in[0];
    const int*   loc_idx  = (const int*)d_in[1];
    const int*   pos_idx  = (const int*)d_in[2];
    const int*   neg_idx  = (const int*)d_in[3];
    const float* ucat     = (const float*)d_in[4];
    const float* utxt     = (const float*)d_in[5];
    const float* lcat     = (const float*)d_in[6];
    const float* ltxt     = (const float*)d_in[7];
    const float* sbert    = (const float*)d_in[8];
    const float* mh       = (const float*)d_in[9];
    const float* Wc1      = (const float*)d_in[10];
    const float* Wc2      = (const float*)d_in[12];
    const float* bc2      = (const float*)d_in[13];
    const float* bc1      = (const float*)d_in[11];
    const float* Wt1      = (const float*)d_in[14];
    const float* bt1      = (const float*)d_in[15];
    const float* Wt2      = (const float*)d_in[16];
    const float* bt2      = (const float*)d_in[17];

    const int Bn     = in_sizes[0];
    const int nbooks = in_sizes[8] / SBD;

    char* ws = (char*)d_ws;
    float* E = (float*)ws;
    size_t off = (size_t)nbooks * EMB * 4;
    off = (off + 255) & ~(size_t)255;
    char* iT1 = ws + off; off += 196608;
    char* iT2 = ws + off; off += 24576;
    char* iC1 = ws + off; off += 16384;
    char* iC2 = ws + off; off += 12288;

    hipLaunchKernelGGL(prep_weights, dim3(64), dim3(256), 0, stream,
                       Wt1, Wt2, Wc1, Wc2, iT1, iT2, iC1, iC2);

    const int nblocksA = (nbooks + MB - 1) / MB;
    hipLaunchKernelGGL(encode_books_mfma, dim3(nblocksA), dim3(256), 0, stream,
                       sbert, mh, iT1, iT2, iC1, iC2, bt1, bt2, bc1, bc2, E, nbooks);

    const int nblocksB = (Bn + 15) / 16;
    hipLaunchKernelGGL(score_kernel, dim3(nblocksB), dim3(256), 0, stream,
                       user_idx, loc_idx, pos_idx, neg_idx,
                       ucat, utxt, lcat, ltxt, E, (float*)d_out, Bn);
}